// Round 8
// baseline (227.408 us; speedup 1.0000x reference)
//
#include <hip/hip_runtime.h>
#include <hip/hip_bf16.h>

// Problem constants
#define B_SZ 32
#define T_SZ 4096
#define H_SZ 256
#define M_SZ (T_SZ * B_SZ)   // 131072 rows; enc is [M][256] dense, m = t*32 + b
#define AROW 260             // LDS row stride in dwords (1040 B: 16B-aligned, +16B pad)

typedef __attribute__((ext_vector_type(8))) short bf16x8;
typedef __attribute__((ext_vector_type(4))) float f32x4;

// fp32 -> bf16 bits, round-to-nearest-even
static __device__ __forceinline__ short f2bf(float x) {
    unsigned u = __float_as_uint(x);
    u += 0x7fffu + ((u >> 16) & 1u);
    return (short)(u >> 16);
}

static __device__ __forceinline__ bf16x8 cvt8(f32x4 a, f32x4 b) {
    bf16x8 r;
    r[0] = f2bf(a[0]); r[1] = f2bf(a[1]); r[2] = f2bf(a[2]); r[3] = f2bf(a[3]);
    r[4] = f2bf(b[0]); r[5] = f2bf(b[1]); r[6] = f2bf(b[2]); r[7] = f2bf(b[3]);
    return r;
}

// Async global->LDS DMA, 16 B per lane. LDS dest = wave-uniform base + lane*16.
// In-flight data costs ZERO VGPRs, so the compiler cannot sink these.
static __device__ __forceinline__ void dma16(const float* g, const uint32_t* l) {
    __builtin_amdgcn_global_load_lds(
        (const __attribute__((address_space(1))) void*)(uintptr_t)g,
        (__attribute__((address_space(3))) void*)(uintptr_t)l,
        16, 0, 0);
}

// Prep: (a) wbf2 = fragment-ordered bf16 We; (b) hpT[h][b] = hidden[b,:].Wh[h,:] + attn_b[h]
// wbf2 short-index for (h,k): (hs*4+nt)*4096 + s*512 + quad*128 + r*8 + e
//   hs=h>>6, nt=(h>>4)&3, r=h&15, s=k>>5, quad=(k>>3)&3, e=k&7
__global__ __launch_bounds__(256) void prep_kernel(
    const float* __restrict__ hidden, const float* __restrict__ attn_w,
    const float* __restrict__ attn_b, float* __restrict__ hpT,
    short* __restrict__ wbf2)
{
    const int h   = blockIdx.x;
    const int tid = threadIdx.x;     // = k for the weight shuffle
    __shared__ float wsh[H_SZ];

    wsh[tid] = attn_w[(size_t)h * 512 + tid];                  // Wh row (coalesced)
    {
        const int k = tid;
        const int hs = h >> 6, nt = (h >> 4) & 3, r = h & 15;
        const int s = k >> 5, quad = (k >> 3) & 3, e = k & 7;
        wbf2[(hs * 4 + nt) * 4096 + s * 512 + quad * 128 + r * 8 + e] =
            f2bf(attn_w[(size_t)h * 512 + 256 + k]);
    }
    __syncthreads();

    const int b  = tid >> 3;
    const int kg = tid & 7;
    const float* hrow = hidden + b * H_SZ + kg * 32;
    const float* wrow = wsh + kg * 32;
    float s = 0.f;
#pragma unroll
    for (int j = 0; j < 32; j += 4) {
        f32x4 hv = *(const f32x4*)(hrow + j);
        s = fmaf(hv[0], wrow[j + 0], s);
        s = fmaf(hv[1], wrow[j + 1], s);
        s = fmaf(hv[2], wrow[j + 2], s);
        s = fmaf(hv[3], wrow[j + 3], s);
    }
#pragma unroll
    for (int off = 1; off < 8; off <<= 1) s += __shfl_xor(s, off, 8);
    if (kg == 0) hpT[h * B_SZ + b] = s + attn_b[h];   // [H][B]
}

// Main: block = 32 contiguous rows of enc[M][256] staged as FP32 via async DMA
// (8 global_load_lds_dwordx4 per wave, zero VGPR cost, all in flight at once).
// 4 waves; wave w owns h-slice [64w,64w+64), rows shared (mt=0,1).
__global__ __launch_bounds__(256, 4) void attn_main(
    const float* __restrict__ enc,    // [M][256]
    const short* __restrict__ wbf2,   // fragment-ordered bf16 We
    const float* __restrict__ hpT,    // [H][B]
    const float* __restrict__ v,      // [H]
    float* __restrict__ scores)       // [B][T]
{
    __shared__ __align__(16) uint32_t At[32 * AROW];  // 33.3 KB fp32 tile
    __shared__ float part[4][32];

    const int blk  = blockIdx.x;
    const int m0   = blk << 5;           // 32 rows per block
    const int tid  = threadIdx.x;
    const int w    = tid >> 6;
    const int lane = tid & 63;
    const int r    = lane & 15;
    const int quad = lane >> 4;
    const int hbase = w * 64;

    // ---- Issue all DMAs: wave w fills rows [8w, 8w+8), 1 KB each ----
    const float* gbase = enc + (size_t)(m0 + 8 * w) * H_SZ + lane * 4;
    const uint32_t* lbase = At + (8 * w) * AROW;
#pragma unroll
    for (int i = 0; i < 8; ++i)
        dma16(gbase + i * H_SZ, lbase + i * AROW);

    // weight fragment pointer: lane-contiguous 1 KB per (nt, kchunk)
    const short* wp = wbf2 + (size_t)w * 16384 + lane * 8;

    // B fragments for chunk 0 (drained by the same barrier)
    bf16x8 bc[4];
#pragma unroll
    for (int nt = 0; nt < 4; ++nt)
        bc[nt] = *(const bf16x8*)(wp + nt * 4096);

    f32x4 acc[2][4];
#pragma unroll
    for (int mt = 0; mt < 2; ++mt)
#pragma unroll
        for (int nt = 0; nt < 4; ++nt)
            acc[mt][nt] = (f32x4){0.f, 0.f, 0.f, 0.f};

    __syncthreads();   // compiler emits s_waitcnt vmcnt(0) before s_barrier

    // ---- K loop: 8 chunks of 32 ----
#pragma unroll
    for (int kc = 0; kc < 8; ++kc) {
        bf16x8 bn[4];
        if (kc < 7) {
#pragma unroll
            for (int nt = 0; nt < 4; ++nt)
                bn[nt] = *(const bf16x8*)(wp + nt * 4096 + (kc + 1) * 512);
        }

        bf16x8 af[2];
#pragma unroll
        for (int mt = 0; mt < 2; ++mt) {
            const uint32_t* a = At + (mt * 16 + r) * AROW + kc * 32 + quad * 8;
            f32x4 lo = *(const f32x4*)a;
            f32x4 hi = *(const f32x4*)(a + 4);
            af[mt] = cvt8(lo, hi);
        }

#pragma unroll
        for (int mt = 0; mt < 2; ++mt)
#pragma unroll
            for (int nt = 0; nt < 4; ++nt)
                acc[mt][nt] = __builtin_amdgcn_mfma_f32_16x16x32_bf16(
                    af[mt], bc[nt], acc[mt][nt], 0, 0, 0);

#pragma unroll
        for (int nt = 0; nt < 4; ++nt) bc[nt] = bn[nt];
    }

    // ---- Epilogue: relu(hpT[h][b(row)] + eproj) dot v, reduce over h ----
    // C/D: col = lane&15 (h), row = mt*16 + quad*4 + reg; b = row (m0 mult of 32)
    float vv[4];
    f32x4 hpv[2][4];
#pragma unroll
    for (int nt = 0; nt < 4; ++nt) {
        const int h = hbase + nt * 16 + r;
        vv[nt] = v[h];
        hpv[0][nt] = *(const f32x4*)(hpT + h * B_SZ + quad * 4);
        hpv[1][nt] = *(const f32x4*)(hpT + h * B_SZ + 16 + quad * 4);
    }

#pragma unroll
    for (int mt = 0; mt < 2; ++mt) {
#pragma unroll
        for (int reg = 0; reg < 4; ++reg) {
            float s = 0.f;
#pragma unroll
            for (int nt = 0; nt < 4; ++nt) {
                float e = hpv[mt][nt][reg] + acc[mt][nt][reg];
                e = fmaxf(e, 0.f);
                s = fmaf(vv[nt], e, s);
            }
#pragma unroll
            for (int off = 1; off < 16; off <<= 1) s += __shfl_xor(s, off, 16);
            if (r == 0) part[w][mt * 16 + quad * 4 + reg] = s;
        }
    }
    __syncthreads();
    if (tid < 32) {
        float sc = part[0][tid] + part[1][tid] + part[2][tid] + part[3][tid];
        const int b = tid;                 // (m0+tid) & 31 == tid
        const int t = (m0 + tid) >> 5;
        scores[b * T_SZ + t] = sc;
    }
}

// Softmax over t (4096) per batch row; 1024 threads
__global__ __launch_bounds__(1024) void softmax_kernel(
    const float* __restrict__ scores, float* __restrict__ out)
{
    const int b   = blockIdx.x;
    const int tid = threadIdx.x;
    const float* s = scores + b * T_SZ;
    float*       o = out    + b * T_SZ;

    float loc[4];
    float m = -3.0e38f;
#pragma unroll
    for (int i = 0; i < 4; ++i) {
        loc[i] = s[tid + i * 1024];
        m = fmaxf(m, loc[i]);
    }
    __shared__ float redm[16], reds[16];
#pragma unroll
    for (int off = 32; off > 0; off >>= 1) m = fmaxf(m, __shfl_xor(m, off, 64));
    if ((tid & 63) == 0) redm[tid >> 6] = m;
    __syncthreads();
#pragma unroll
    for (int i = 0; i < 16; ++i) m = fmaxf(m, redm[i]);

    float sum = 0.f;
#pragma unroll
    for (int i = 0; i < 4; ++i) {
        loc[i] = __expf(loc[i] - m);
        sum += loc[i];
    }
#pragma unroll
    for (int off = 32; off > 0; off >>= 1) sum += __shfl_xor(sum, off, 64);
    if ((tid & 63) == 0) reds[tid >> 6] = sum;
    __syncthreads();
    sum = 0.f;
#pragma unroll
    for (int i = 0; i < 16; ++i) sum += reds[i];
    const float inv = 1.0f / sum;
#pragma unroll
    for (int i = 0; i < 4; ++i) o[tid + i * 1024] = loc[i] * inv;
}

extern "C" void kernel_launch(void* const* d_in, const int* in_sizes, int n_in,
                              void* d_out, int out_size, void* d_ws, size_t ws_size,
                              hipStream_t stream) {
    const float* hidden = (const float*)d_in[0];   // [B,H]
    const float* enc    = (const float*)d_in[1];   // [T,B,H] == [M][256]
    const float* attn_w = (const float*)d_in[2];   // [H,2H]
    const float* attn_b = (const float*)d_in[3];   // [H]
    const float* v      = (const float*)d_in[4];   // [H]
    float* out = (float*)d_out;                    // [B,1,T]

    float* hpT    = (float*)d_ws;                  // [H][B]   32 KB
    float* scores = hpT + H_SZ * B_SZ;             // [B][T]   512 KB
    short* wbf2   = (short*)(scores + B_SZ * T_SZ);// 128 KB fragment-ordered

    hipLaunchKernelGGL(prep_kernel, dim3(H_SZ), dim3(256), 0, stream,
                       hidden, attn_w, attn_b, hpT, wbf2);
    hipLaunchKernelGGL(attn_main, dim3(M_SZ / 32), dim3(256), 0, stream,
                       enc, wbf2, hpT, v, scores);
    hipLaunchKernelGGL(softmax_kernel, dim3(B_SZ), dim3(1024), 0, stream,
                       scores, out);
}

// Round 9
// 214.899 us; speedup vs baseline: 1.0582x; 1.0582x over previous
//
#include <hip/hip_runtime.h>
#include <hip/hip_bf16.h>

// Problem constants
#define B_SZ 32
#define T_SZ 4096
#define H_SZ 256
#define M_SZ (T_SZ * B_SZ)   // 131072 rows; enc is [M][256] dense, m = t*32 + b
#define SROW 72              // shorts per LDS row: 64 k + 8 pad

typedef __attribute__((ext_vector_type(8))) short bf16x8;
typedef __attribute__((ext_vector_type(4))) short bf16x4;
typedef __attribute__((ext_vector_type(4))) float f32x4;

// fp32 -> bf16 bits, round-to-nearest-even
static __device__ __forceinline__ short f2bf(float x) {
    unsigned u = __float_as_uint(x);
    u += 0x7fffu + ((u >> 16) & 1u);
    return (short)(u >> 16);
}

static __device__ __forceinline__ bf16x4 cvt4(f32x4 a) {
    bf16x4 r;
    r[0] = f2bf(a[0]); r[1] = f2bf(a[1]); r[2] = f2bf(a[2]); r[3] = f2bf(a[3]);
    return r;
}

// Prep: (a) wbf2 = fragment-ordered bf16 We; (b) hpT[h][b] = hidden[b,:].Wh[h,:] + attn_b[h]
// wbf2 short-index for (h,k): (hs*4+nt)*4096 + s*512 + quad*128 + r*8 + e
//   hs=h>>6, nt=(h>>4)&3, r=h&15, s=k>>5, quad=(k>>3)&3, e=k&7
__global__ __launch_bounds__(256) void prep_kernel(
    const float* __restrict__ hidden, const float* __restrict__ attn_w,
    const float* __restrict__ attn_b, float* __restrict__ hpT,
    short* __restrict__ wbf2)
{
    const int h   = blockIdx.x;
    const int tid = threadIdx.x;     // = k for the weight shuffle
    __shared__ float wsh[H_SZ];

    wsh[tid] = attn_w[(size_t)h * 512 + tid];                  // Wh row (coalesced)
    {
        const int k = tid;
        const int hs = h >> 6, nt = (h >> 4) & 3, r = h & 15;
        const int s = k >> 5, quad = (k >> 3) & 3, e = k & 7;
        wbf2[(hs * 4 + nt) * 4096 + s * 512 + quad * 128 + r * 8 + e] =
            f2bf(attn_w[(size_t)h * 512 + 256 + k]);
    }
    __syncthreads();

    const int b  = tid >> 3;
    const int kg = tid & 7;
    const float* hrow = hidden + b * H_SZ + kg * 32;
    const float* wrow = wsh + kg * 32;
    float s = 0.f;
#pragma unroll
    for (int j = 0; j < 32; j += 4) {
        f32x4 hv = *(const f32x4*)(hrow + j);
        s = fmaf(hv[0], wrow[j + 0], s);
        s = fmaf(hv[1], wrow[j + 1], s);
        s = fmaf(hv[2], wrow[j + 2], s);
        s = fmaf(hv[3], wrow[j + 3], s);
    }
#pragma unroll
    for (int off = 1; off < 8; off <<= 1) s += __shfl_xor(s, off, 8);
    if (kg == 0) hpT[h * B_SZ + b] = s + attn_b[h];   // [H][B]
}

// Main: block = 64 contiguous rows of enc[M][256]. 4 waves, wave w owns h-slice
// [64w,64w+64). K pipelined in 4 chunks of 64, double-buffered LDS.
// All global loads lane-contiguous; enc via NT loads (best-measured variant, R6).
__global__ __launch_bounds__(256, 3) void attn_main(
    const float* __restrict__ enc,    // [M][256]
    const short* __restrict__ wbf2,   // fragment-ordered bf16 We
    const float* __restrict__ hpT,    // [H][B]
    const float* __restrict__ v,      // [H]
    float* __restrict__ scores)       // [B][T]
{
    __shared__ __align__(16) short As[2][64 * SROW];  // 2 x 9216 B
    __shared__ float part[4][64];

    const int blk  = blockIdx.x;
    const int m0   = blk << 6;
    const int tid  = threadIdx.x;
    const int w    = tid >> 6;
    const int lane = tid & 63;
    const int r    = lane & 15;
    const int quad = lane >> 4;
    const int hbase = w * 64;

    // staging map: quarter-wave = one contiguous 256B row-slice.
    const int sr  = tid >> 4;          // 0..15
    const int sc4 = (tid & 15) * 4;    // 0..60
    const float* sp = enc + (size_t)(m0 + sr) * H_SZ + sc4;
    short* sdB[2];
    sdB[0] = &As[0][0] + sr * SROW + sc4;
    sdB[1] = &As[1][0] + sr * SROW + sc4;

    // weight fragment pointers: contiguous across lanes
    const short* wp = wbf2 + (size_t)w * 16384 + lane * 8;   // + nt*4096 + (kc*2+ss)*512

    f32x4 acc[4][4];
#pragma unroll
    for (int mt = 0; mt < 4; ++mt)
#pragma unroll
        for (int nt = 0; nt < 4; ++nt)
            acc[mt][nt] = (f32x4){0.f, 0.f, 0.f, 0.f};

    // ---- Prologue: stage chunk 0 (NT loads), load B(chunk 0) ----
    f32x4 g[4];
#pragma unroll
    for (int i = 0; i < 4; ++i)
        g[i] = __builtin_nontemporal_load((const f32x4*)(sp + i * 16 * H_SZ));

    bf16x8 bc[2][4];
#pragma unroll
    for (int ss = 0; ss < 2; ++ss)
#pragma unroll
        for (int nt = 0; nt < 4; ++nt)
            bc[ss][nt] = *(const bf16x8*)(wp + nt * 4096 + ss * 512);

#pragma unroll
    for (int i = 0; i < 4; ++i)
        *(bf16x4*)(sdB[0] + i * 16 * SROW) = cvt4(g[i]);
    __syncthreads();

    // ---- Pipelined main loop: 4 chunks of 64 k ----
#pragma unroll
    for (int kc = 0; kc < 4; ++kc) {
        f32x4 gn[4];
        if (kc < 3) {
#pragma unroll
            for (int i = 0; i < 4; ++i)
                gn[i] = __builtin_nontemporal_load(
                    (const f32x4*)(sp + i * 16 * H_SZ + (kc + 1) * 64));
        }

        const short* abase = &As[kc & 1][0] + quad * 8;
#pragma unroll
        for (int ss = 0; ss < 2; ++ss) {
            bf16x8 af[4];
#pragma unroll
            for (int mt = 0; mt < 4; ++mt)
                af[mt] = *(const bf16x8*)(abase + (mt * 16 + r) * SROW + ss * 32);
#pragma unroll
            for (int mt = 0; mt < 4; ++mt)
#pragma unroll
                for (int nt = 0; nt < 4; ++nt)
                    acc[mt][nt] = __builtin_amdgcn_mfma_f32_16x16x32_bf16(
                        af[mt], bc[ss][nt], acc[mt][nt], 0, 0, 0);
        }

        if (kc < 3) {
            const int ko = (kc + 1) * 2;
#pragma unroll
            for (int ss = 0; ss < 2; ++ss)
#pragma unroll
                for (int nt = 0; nt < 4; ++nt)
                    bc[ss][nt] = *(const bf16x8*)(wp + nt * 4096 + (ko + ss) * 512);

            short* d = sdB[(kc + 1) & 1];
#pragma unroll
            for (int i = 0; i < 4; ++i)
                *(bf16x4*)(d + i * 16 * SROW) = cvt4(gn[i]);
            __syncthreads();
        }
    }

    // ---- Epilogue: relu(hpT[h][b(row)] + eproj) dot v, reduce over h ----
    float vv[4];
    f32x4 hpv[2][4];
#pragma unroll
    for (int nt = 0; nt < 4; ++nt) {
        const int h = hbase + nt * 16 + r;
        vv[nt] = v[h];
        hpv[0][nt] = *(const f32x4*)(hpT + h * B_SZ + quad * 4);
        hpv[1][nt] = *(const f32x4*)(hpT + h * B_SZ + 16 + quad * 4);
    }

#pragma unroll
    for (int mt = 0; mt < 4; ++mt) {
#pragma unroll
        for (int reg = 0; reg < 4; ++reg) {
            float s = 0.f;
#pragma unroll
            for (int nt = 0; nt < 4; ++nt) {
                float e = hpv[mt & 1][nt][reg] + acc[mt][nt][reg];
                e = fmaxf(e, 0.f);
                s = fmaf(vv[nt], e, s);
            }
#pragma unroll
            for (int off = 1; off < 16; off <<= 1) s += __shfl_xor(s, off, 16);
            if (r == 0) part[w][mt * 16 + quad * 4 + reg] = s;
        }
    }
    __syncthreads();
    if (tid < 64) {
        float sc = part[0][tid] + part[1][tid] + part[2][tid] + part[3][tid];
        const int b = tid & 31;
        const int t = (m0 + tid) >> 5;
        scores[b * T_SZ + t] = sc;
    }
}

// Softmax over t (4096) per batch row; 1024 threads
__global__ __launch_bounds__(1024) void softmax_kernel(
    const float* __restrict__ scores, float* __restrict__ out)
{
    const int b   = blockIdx.x;
    const int tid = threadIdx.x;
    const float* s = scores + b * T_SZ;
    float*       o = out    + b * T_SZ;

    float loc[4];
    float m = -3.0e38f;
#pragma unroll
    for (int i = 0; i < 4; ++i) {
        loc[i] = s[tid + i * 1024];
        m = fmaxf(m, loc[i]);
    }
    __shared__ float redm[16], reds[16];
#pragma unroll
    for (int off = 32; off > 0; off >>= 1) m = fmaxf(m, __shfl_xor(m, off, 64));
    if ((tid & 63) == 0) redm[tid >> 6] = m;
    __syncthreads();
#pragma unroll
    for (int i = 0; i < 16; ++i) m = fmaxf(m, redm[i]);

    float sum = 0.f;
#pragma unroll
    for (int i = 0; i < 4; ++i) {
        loc[i] = __expf(loc[i] - m);
        sum += loc[i];
    }
#pragma unroll
    for (int off = 32; off > 0; off >>= 1) sum += __shfl_xor(sum, off, 64);
    if ((tid & 63) == 0) reds[tid >> 6] = sum;
    __syncthreads();
    sum = 0.f;
#pragma unroll
    for (int i = 0; i < 16; ++i) sum += reds[i];
    const float inv = 1.0f / sum;
#pragma unroll
    for (int i = 0; i < 4; ++i) o[tid + i * 1024] = loc[i] * inv;
}

extern "C" void kernel_launch(void* const* d_in, const int* in_sizes, int n_in,
                              void* d_out, int out_size, void* d_ws, size_t ws_size,
                              hipStream_t stream) {
    const float* hidden = (const float*)d_in[0];   // [B,H]
    const float* enc    = (const float*)d_in[1];   // [T,B,H] == [M][256]
    const float* attn_w = (const float*)d_in[2];   // [H,2H]
    const float* attn_b = (const float*)d_in[3];   // [H]
    const float* v      = (const float*)d_in[4];   // [H]
    float* out = (float*)d_out;                    // [B,1,T]

    float* hpT    = (float*)d_ws;                  // [H][B]   32 KB
    float* scores = hpT + H_SZ * B_SZ;             // [B][T]   512 KB
    short* wbf2   = (short*)(scores + B_SZ * T_SZ);// 128 KB fragment-ordered

    hipLaunchKernelGGL(prep_kernel, dim3(H_SZ), dim3(256), 0, stream,
                       hidden, attn_w, attn_b, hpT, wbf2);
    hipLaunchKernelGGL(attn_main, dim3(M_SZ / 64), dim3(256), 0, stream,
                       enc, wbf2, hpT, v, scores);
    hipLaunchKernelGGL(softmax_kernel, dim3(B_SZ), dim3(1024), 0, stream,
                       scores, out);
}